// Round 9
// baseline (198.830 us; speedup 1.0000x reference)
//
#include <hip/hip_runtime.h>
#include <hip/hip_bf16.h>
#include <cstdint>

#define T_SEQ   2048
#define DMODEL  1024
#define NHEADS  16
#define DHEAD   64
#define B_SZ    4
#define M_ROWS  (B_SZ * T_SEQ)   // 8192
// Q pre-scale: (1/sqrt(64)) * log2(e)  -> softmax via exp2 is exact e^S
#define QSCALE  0.1803368801111204f

typedef unsigned short u16;
typedef __attribute__((ext_vector_type(8))) __bf16 bf16x8;
typedef __attribute__((ext_vector_type(4))) float  f32x4;

__device__ __forceinline__ u16 f2bf(float f) {
  uint32_t u = __float_as_uint(f);
  u += 0x7FFF + ((u >> 16) & 1);       // RNE
  return (u16)(u >> 16);
}

__device__ __forceinline__ float fast_exp2(float x) {
  return __builtin_amdgcn_exp2f(x);    // v_exp_f32 (D = 2^S0)
}

__device__ __forceinline__ void gload_lds16(const void* g, void* l) {
  __builtin_amdgcn_global_load_lds(
      (const __attribute__((address_space(1))) void*)g,
      (__attribute__((address_space(3))) void*)l, 16, 0, 0);
}

#define BAR  __builtin_amdgcn_s_barrier()
#define LG0  asm volatile("s_waitcnt lgkmcnt(0)" ::: "memory")
#define VM3  asm volatile("s_waitcnt vmcnt(3)" ::: "memory")
#define VM0  asm volatile("s_waitcnt vmcnt(0)" ::: "memory")
#define PRIO1 __builtin_amdgcn_s_setprio(1)
#define PRIO0 __builtin_amdgcn_s_setprio(0)

// ---------------- fused f32 -> bf16 convert (x + all 4 weights) -------------
__global__ void cvt_all(const float* __restrict__ x,  const float* __restrict__ Wq,
                        const float* __restrict__ Wk, const float* __restrict__ Wv,
                        const float* __restrict__ Wo, u16* __restrict__ xb,
                        u16* __restrict__ Wb) {
  const int NX = (B_SZ * T_SEQ * DMODEL) / 8;   // 1048576 vec8
  const int NW = (DMODEL * DMODEL) / 8;         // 131072 vec8
  int i = blockIdx.x * blockDim.x + threadIdx.x;
  int stride = gridDim.x * blockDim.x;
  for (; i < NX + 4 * NW; i += stride) {
    const float* src; u16* dst; int idx;
    if (i < NX) { src = x; dst = xb; idx = i; }
    else {
      int j = i - NX, w = j >> 17;  // NW = 2^17
      idx = j & (NW - 1);
      src = (w == 0) ? Wq : (w == 1) ? Wk : (w == 2) ? Wv : Wo;
      dst = Wb + (size_t)w * (DMODEL * DMODEL);
    }
    const float4* s4 = (const float4*)src;
    float4 a = s4[2 * idx], b = s4[2 * idx + 1];
    union { u16 u[8]; uint4 v; } o;
    o.u[0] = f2bf(a.x); o.u[1] = f2bf(a.y); o.u[2] = f2bf(a.z); o.u[3] = f2bf(a.w);
    o.u[4] = f2bf(b.x); o.u[5] = f2bf(b.y); o.u[6] = f2bf(b.z); o.u[7] = f2bf(b.w);
    ((uint4*)dst)[idx] = o.v;
  }
}

// ---------------- 256x192 8-phase QKV GEMM ----------------------------------
// C[i,j] = sum_k A[i,k]*W[j,k], M=8192, N=3072, K=1024.
// Grid 512 blocks (32 tm x 16 tn) = 2 EXACT rounds at 1 block/CU (no tail).
// 512 thr = 8 waves (2M x 4N), per-wave 128x48 out (acc[8][3], 96 VGPR).
// LDS 112KB: 2dbuf x (A[256][64] + B[192][64]). Stage unit = 64 rows = 8KB
// = 1 gload/thread. Per 2-K-tile iter: 14 units over 8 phases; vmcnt(3) at
// ph4/ph8 (outstanding = 3 newest units after the needed tile's last unit).
// Clusters of 12 MFMA (4m x 3n x 1kk); B-frags reused across 2 phases.
// XOR-swizzle: source col-chunk ^ (row&7), read chunk ^ (lrow&7).
__global__ __launch_bounds__(512, 2) void gemm8p_qkv(
    const u16* __restrict__ A, const u16* __restrict__ Wall,
    u16* __restrict__ Qb, u16* __restrict__ Kb, u16* __restrict__ Vtb) {
  constexpr int K = DMODEL;          // 1024, 16 K-tiles of BK=64
  __shared__ u16 As[2][256 * 64];
  __shared__ u16 Bs[2][192 * 64];
  const int tid = threadIdx.x;
  const int wid = tid >> 6, lane = tid & 63;
  const int wr = wid >> 2, wc = wid & 3;       // 2M x 4N waves
  const int flat = blockIdx.x;
  const int xcd = flat & 7, serial = flat >> 3;
  const int tm = (serial >> 4) * 8 + xcd;      // 0..31 (512%8==0, bijective)
  const int tn = serial & 15;                  // 0..15
  const int lrow = lane & 15, lq = lane >> 4;
  const int sr = lrow & 7;
  const int srow = tid >> 3;                   // 0..63 staging row in unit
  const int csw = ((tid & 7) ^ (srow & 7)) * 8;
  const int cha = (tid & 7) * 8;               // linear LDS dest chunk

  const u16* Arow = A    + (size_t)(tm * 256 + srow) * K + csw;
  const u16* Brow = Wall + (size_t)(tn * 192 + srow) * K + csw;

  auto stageAu = [&](int kt, int d, int u) {
    gload_lds16(Arow + (size_t)(u * 64) * K + kt, &As[d][(u * 64 + srow) * 64 + cha]);
  };
  auto stageBu = [&](int kt, int d, int u) {
    gload_lds16(Brow + (size_t)(u * 64) * K + kt, &Bs[d][(u * 64 + srow) * 64 + cha]);
  };

  f32x4 acc[8][3];
#pragma unroll
  for (int m = 0; m < 8; m++)
#pragma unroll
    for (int n = 0; n < 3; n++) acc[m][n] = f32x4{0.f, 0.f, 0.f, 0.f};

  auto ldA = [&](bf16x8 (&a)[4], int d, int mb, int kk) {
#pragma unroll
    for (int m = 0; m < 4; m++)
      a[m] = *(const bf16x8*)&As[d][(wr * 128 + (mb + m) * 16 + lrow) * 64 + (((kk * 4 + lq) ^ sr) * 8)];
  };
  auto ldB = [&](bf16x8 (&b)[3], int d, int kk) {
#pragma unroll
    for (int n = 0; n < 3; n++)
      b[n] = *(const bf16x8*)&Bs[d][(wc * 48 + n * 16 + lrow) * 64 + (((kk * 4 + lq) ^ sr) * 8)];
  };
  auto cl = [&](bf16x8 (&a)[4], bf16x8 (&b)[3], int mb) {
#pragma unroll
    for (int m = 0; m < 4; m++)
#pragma unroll
      for (int n = 0; n < 3; n++)
        acc[mb + m][n] = __builtin_amdgcn_mfma_f32_16x16x32_bf16(a[m], b[n], acc[mb + m][n], 0, 0, 0);
  };

  // prologue: t0 fully (A 4u + B 3u) + t1's B (3u); wait t0 (outstanding=3)
  stageAu(0, 0, 0); stageAu(0, 0, 1); stageAu(0, 0, 2); stageAu(0, 0, 3);
  stageBu(0, 0, 0); stageBu(0, 0, 1); stageBu(0, 0, 2);
  stageBu(64, 1, 0); stageBu(64, 1, 1); stageBu(64, 1, 2);
  VM3;
  BAR;

#pragma unroll
  for (int i = 0; i < 8; ++i) {
    const int t1k = (2 * i + 1) * 64;
    const int u0 = 2 * i + 2, u1 = 2 * i + 3;
    const int u0k = u0 * 64, u1k = u1 * 64;
    bf16x8 aqA[4], aqB[4], bq0[3], bq1[3];
    // ph1: t0 (mb0,kk0)
    ldA(aqA, 0, 0, 0); ldB(bq0, 0, 0);
    stageAu(t1k, 1, 0); stageAu(t1k, 1, 1);
    BAR; LG0; PRIO1; cl(aqA, bq0, 0); PRIO0; BAR;
    // ph2: t0 (mb0,kk1)
    ldA(aqB, 0, 0, 1); ldB(bq1, 0, 1);
    stageAu(t1k, 1, 2); stageAu(t1k, 1, 3);
    BAR; LG0; PRIO1; cl(aqB, bq1, 0); PRIO0; BAR;
    // ph3: t0 (mb1,kk1)  [reuse bq1]
    ldA(aqA, 0, 4, 1);
    if (u0 < 16) { stageBu(u0k, 0, 0); stageBu(u0k, 0, 1); }
    BAR; LG0; PRIO1; cl(aqA, bq1, 4); PRIO0; BAR;
    // ph4: t0 (mb1,kk0)  [reuse bq0]; wait t1 landed (keep 3 newest in flight)
    ldA(aqB, 0, 4, 0);
    if (u0 < 16) stageBu(u0k, 0, 2);
    BAR; LG0; PRIO1; cl(aqB, bq0, 4); PRIO0;
    if (i < 7) { VM3; } else { VM0; }
    BAR;
    // ph5: t1 (mb0,kk0)
    ldA(aqA, 1, 0, 0); ldB(bq0, 1, 0);
    if (u0 < 16) { stageAu(u0k, 0, 0); stageAu(u0k, 0, 1); }
    BAR; LG0; PRIO1; cl(aqA, bq0, 0); PRIO0; BAR;
    // ph6: t1 (mb0,kk1)
    ldA(aqB, 1, 0, 1); ldB(bq1, 1, 1);
    if (u0 < 16) { stageAu(u0k, 0, 2); stageAu(u0k, 0, 3); }
    BAR; LG0; PRIO1; cl(aqB, bq1, 0); PRIO0; BAR;
    // ph7: t1 (mb1,kk1)
    ldA(aqA, 1, 4, 1);
    if (u1 < 16) { stageBu(u1k, 1, 0); stageBu(u1k, 1, 1); }
    BAR; LG0; PRIO1; cl(aqA, bq1, 4); PRIO0; BAR;
    // ph8: t1 (mb1,kk0); wait u0 landed
    ldA(aqB, 1, 4, 0);
    if (u1 < 16) stageBu(u1k, 1, 2);
    BAR; LG0; PRIO1; cl(aqB, bq0, 4); PRIO0;
    if (i < 7) { VM3; }
    BAR;
  }

  // epilogue: scatter to Q/K/Vt; y computed PER ELEMENT (192-col stripe can
  // straddle the 1024 boundaries between Q/K/V).
#pragma unroll
  for (int m = 0; m < 8; m++)
#pragma unroll
    for (int n = 0; n < 3; n++)
#pragma unroll
      for (int v = 0; v < 4; v++) {
        int i_ = tm * 256 + wr * 128 + m * 16 + lq * 4 + v;
        int j  = tn * 192 + wc * 48 + n * 16 + lrow;
        int y = j >> 10, jj = j & 1023;
        int h_ = jj >> 6, d_ = jj & 63;
        int b_ = i_ >> 11, t_ = i_ & 2047;
        float val = acc[m][n][v] * (y == 0 ? QSCALE : 1.0f);
        if (y == 2)
          Vtb[((size_t)(b_ * NHEADS + h_) * 64 + d_) * T_SEQ + t_] = f2bf(val);
        else
          ((y == 0) ? Qb : Kb)[((size_t)(b_ * NHEADS + h_) * T_SEQ + t_) * 64 + d_] = f2bf(val);
      }
}

// ---------------- counted-vmcnt 128x128 NT GEMM (Wo projection) -------------
__global__ __launch_bounds__(256) void gemm3(
    const u16* __restrict__ A, const u16* __restrict__ Wall,
    float* __restrict__ C0) {
  constexpr int K = DMODEL;
  constexpr int NTILES = K / 64;
  constexpr int NT = 8;
  __shared__ u16 As[2][128 * 64];
  __shared__ u16 Bs[2][128 * 64];
  const int tid = threadIdx.x;
  const int wid = tid >> 6, lane = tid & 63;
  const int flat = blockIdx.x;
  const int xcd = flat & 7, serial = flat >> 3;
  const int tm = (serial / NT) * 8 + xcd;
  const int tn = serial % NT;
  const int wr = wid >> 1, wc = wid & 1;
  const int lrow = lane & 15, lq = lane >> 4;
  const int sr = lrow & 7;
  const int srow = lane >> 3;
  const int csw = ((lane & 7) ^ srow) * 8;

  const u16* Arow = A    + (size_t)(tm * 128 + srow) * K + csw;
  const u16* Wrow = Wall + (size_t)(tn * 128 + srow) * K + csw;

  auto stage = [&](int k0, int b) {
#pragma unroll
    for (int it = 0; it < 4; ++it) {
      int rbase = it * 32 + wid * 8;
      gload_lds16(Arow + (size_t)rbase * K + k0, &As[b][rbase * 64]);
      gload_lds16(Wrow + (size_t)rbase * K + k0, &Bs[b][rbase * 64]);
    }
  };

  f32x4 acc[4][4];
#pragma unroll
  for (int m = 0; m < 4; m++)
#pragma unroll
    for (int n = 0; n < 4; n++) acc[m][n] = f32x4{0.f, 0.f, 0.f, 0.f};

  auto compute = [&](int b) {
#pragma unroll
    for (int kk = 0; kk < 2; ++kk) {
      bf16x8 a[4], bb[4];
      const int co = ((kk * 4 + lq) ^ sr) * 8;
#pragma unroll
      for (int m = 0; m < 4; m++)
        a[m] = *(const bf16x8*)&As[b][(wr * 64 + m * 16 + lrow) * 64 + co];
#pragma unroll
      for (int n = 0; n < 4; n++)
        bb[n] = *(const bf16x8*)&Bs[b][(wc * 64 + n * 16 + lrow) * 64 + co];
#pragma unroll
      for (int m = 0; m < 4; m++)
#pragma unroll
        for (int n = 0; n < 4; n++)
          acc[m][n] = __builtin_amdgcn_mfma_f32_16x16x32_bf16(a[m], bb[n], acc[m][n], 0, 0, 0);
    }
  };

  stage(0, 0);
  stage(64, 1);
  asm volatile("s_waitcnt vmcnt(8)" ::: "memory");
  __builtin_amdgcn_s_barrier();

  for (int t = 0; t < NTILES; t += 2) {
    compute(0);
    asm volatile("" ::: "memory");
    __builtin_amdgcn_s_barrier();
    if (t + 2 < NTILES) {
      stage((t + 2) * 64, 0);
      asm volatile("s_waitcnt vmcnt(8)" ::: "memory");
    } else {
      asm volatile("s_waitcnt vmcnt(0)" ::: "memory");
    }
    __builtin_amdgcn_s_barrier();
    compute(1);
    if (t + 3 < NTILES) {
      asm volatile("" ::: "memory");
      __builtin_amdgcn_s_barrier();
      stage((t + 3) * 64, 1);
      asm volatile("s_waitcnt vmcnt(8)" ::: "memory");
      __builtin_amdgcn_s_barrier();
    }
  }

#pragma unroll
  for (int m = 0; m < 4; m++)
#pragma unroll
    for (int n = 0; n < 4; n++)
#pragma unroll
      for (int v = 0; v < 4; v++) {
        int i = tm * 128 + wr * 64 + m * 16 + lq * 4 + v;
        int j = tn * 128 + wc * 64 + n * 16 + lrow;
        C0[(size_t)i * DMODEL + j] = acc[m][n][v];
      }
}

// ---------------- causal flash attention (unchanged) ------------------------
__global__ __launch_bounds__(256) void flash_attn(
    const u16* __restrict__ Q, const u16* __restrict__ Kg,
    const u16* __restrict__ Vt, u16* __restrict__ Ao) {
  __shared__ u16 Ks[2][64 * 64];
  __shared__ u16 Vs[2][64 * 64];
  __shared__ u16 Ps[4][16 * 64];
  const int tid = threadIdx.x, wid = tid >> 6, lane = tid & 63;
  const int flat = blockIdx.x;
  const int serial = flat >> 3;
  const int bh = (serial >> 4) * 8 + (flat & 7);
  const int qi = serial & 15;
  const int qtA = qi, qtB = 31 - qi;
  const int lrow = lane & 15, lq = lane >> 4;
  const int sr = lrow & 7;
  const int srow = lane >> 3;
  const int csw = ((lane & 7) ^ srow) * 8;

  const u16* qbase = Q + ((size_t)bh * T_SEQ + wid * 16 + lrow) * 64 + lq * 8;
  const bf16x8 qA0 = *(const bf16x8*)(qbase + (size_t)qtA * 4096);
  const bf16x8 qA1 = *(const bf16x8*)(qbase + (size_t)qtA * 4096 + 32);
  const bf16x8 qB0 = *(const bf16x8*)(qbase + (size_t)qtB * 4096);
  const bf16x8 qB1 = *(const bf16x8*)(qbase + (size_t)qtB * 4096 + 32);

  bf16x8 ones;
  {
    union { u16 u; __bf16 b; } c; c.u = 0x3F80;
#pragma unroll
    for (int j = 0; j < 8; j++) ones[j] = c.b;
  }

  f32x4 poA[4], poB[4], lA, lB;
#pragma unroll
  for (int n = 0; n < 4; n++) { poA[n] = f32x4{0.f,0.f,0.f,0.f}; poB[n] = f32x4{0.f,0.f,0.f,0.f}; }
  lA = f32x4{0.f,0.f,0.f,0.f}; lB = f32x4{0.f,0.f,0.f,0.f};

  auto stage = [&](int kt, int b) {
#pragma unroll
    for (int it = 0; it < 2; ++it) {
      int rbase = it * 32 + wid * 8;
      gload_lds16(Kg + ((size_t)bh * T_SEQ + kt * 64 + rbase + srow) * 64 + csw,
                  &Ks[b][rbase * 64]);
      gload_lds16(Vt + ((size_t)bh * 64 + rbase + srow) * T_SEQ + kt * 64 + csw,
                  &Vs[b][rbase * 64]);
    }
  };

  stage(0, 0);
  __syncthreads();
  int cur = 0;

  for (int kt = 0; kt <= qtB; ++kt) {
    if (kt < qtB) stage(kt + 1, cur ^ 1);

    bf16x8 kf0[4], kf1[4];
#pragma unroll
    for (int n = 0; n < 4; n++) {
      kf0[n] = *(const bf16x8*)&Ks[cur][(n * 16 + lrow) * 64 + ((lq ^ sr) * 8)];
      kf1[n] = *(const bf16x8*)&Ks[cur][(n * 16 + lrow) * 64 + (((lq + 4) ^ sr) * 8)];
    }

    auto apply = [&](const bf16x8& q0, const bf16x8& q1,
                     f32x4 (&po)[4], f32x4& l4, bool diag) {
      f32x4 s[4];
#pragma unroll
      for (int n = 0; n < 4; n++) {
        f32x4 a = f32x4{0.f, 0.f, 0.f, 0.f};
        a = __builtin_amdgcn_mfma_f32_16x16x32_bf16(q0, kf0[n], a, 0, 0, 0);
        a = __builtin_amdgcn_mfma_f32_16x16x32_bf16(q1, kf1[n], a, 0, 0, 0);
        s[n] = a;
      }
      if (diag) {
#pragma unroll
        for (int n = 0; n < 4; n++)
#pragma unroll
          for (int v = 0; v < 4; v++) {
            int kcol = n * 16 + lrow;
            int qrow = wid * 16 + lq * 4 + v;
            if (kcol > qrow) s[n][v] = -1e30f;
          }
      }
#pragma unroll
      for (int n = 0; n < 4; n++)
#pragma unroll
        for (int v = 0; v < 4; v++) {
          float p = fast_exp2(s[n][v]);
          int col = n * 16 + lrow;
          int r = lq * 4 + v;
          Ps[wid][r * 64 + (((col >> 3) ^ (r & 7)) * 8) + (col & 7)] =
              (u16)(__float_as_uint(p) >> 16);
        }
#pragma unroll
      for (int kk = 0; kk < 2; kk++) {
        bf16x8 pa = *(const bf16x8*)&Ps[wid][lrow * 64 + (((kk * 4 + lq) ^ sr) * 8)];
#pragma unroll
        for (int n = 0; n < 4; n++) {
          bf16x8 vf = *(const bf16x8*)&Vs[cur][(n * 16 + lrow) * 64 + (((kk * 4 + lq) ^ sr) * 8)];
          po[n] = __builtin_amdgcn_mfma_f32_16x16x32_bf16(pa, vf, po[n], 0, 0, 0);
        }
        l4 = __builtin_amdgcn_mfma_f32_16x16x32_bf16(pa, ones, l4, 0, 0, 0);
      }
    };

    if (kt <= qtA) apply(qA0, qA1, poA, lA, kt == qtA);
    apply(qB0, qB1, poB, lB, kt == qtB);

    asm volatile("s_waitcnt vmcnt(0)" ::: "memory");
    __syncthreads();
    cur ^= 1;
  }

  const int b_ = bh >> 4, h_ = bh & 15;
  auto epi = [&](int qt_, f32x4 (&po)[4], f32x4& l4) {
    float rl[4];
#pragma unroll
    for (int v = 0; v < 4; v++) rl[v] = 1.0f / l4[v];
#pragma unroll
    for (int n = 0; n < 4; n++)
#pragma unroll
      for (int v = 0; v < 4; v++) {
        int t_ = qt_ * 64 + wid * 16 + lq * 4 + v;
        int col = h_ * 64 + n * 16 + lrow;
        Ao[((size_t)b_ * T_SEQ + t_) * DMODEL + col] = f2bf(po[n][v] * rl[v]);
      }
  };
  epi(qtA, poA, lA);
  epi(qtB, poB, lB);
}

// ---------------- launch -----------------------------------------------------
extern "C" void kernel_launch(void* const* d_in, const int* in_sizes, int n_in,
                              void* d_out, int out_size, void* d_ws, size_t ws_size,
                              hipStream_t stream) {
  const float* x  = (const float*)d_in[0];
  const float* Wq = (const float*)d_in[1];
  const float* Wk = (const float*)d_in[2];
  const float* Wv = (const float*)d_in[3];
  const float* Wo = (const float*)d_in[4];
  float* out = (float*)d_out;

  char* ws = (char*)d_ws;
  u16* xb  = (u16*)(ws);                       // 16.78 MB, reused as attn-out
  u16* Wb  = (u16*)(ws + 16777216);            // 4 x 2 MB bf16 weights (QKV contiguous)
  u16* Qb  = (u16*)(ws + 25165824);            // [BH,T,64]
  u16* Kb  = (u16*)(ws + 41943040);            // [BH,T,64]
  u16* Vtb = (u16*)(ws + 58720256);            // [BH,64,T]
  u16* Aob = xb;                               // attn output, bf16 [B*T, 1024]

  cvt_all<<<2048, 256, 0, stream>>>(x, Wq, Wk, Wv, Wo, xb, Wb);

  // fused QKV: M=8192 x N=3072, 256x192 tiles -> 512 blocks = 2 exact rounds
  gemm8p_qkv<<<512, 512, 0, stream>>>(xb, Wb, Qb, Kb, Vtb);

  flash_attn<<<1024, 256, 0, stream>>>(Qb, Kb, Vtb, Aob);

  gemm3<<<512, 256, 0, stream>>>(Aob, Wb + 3 * 1048576, out);
}

// Round 10
// 185.978 us; speedup vs baseline: 1.0691x; 1.0691x over previous
//
#include <hip/hip_runtime.h>
#include <hip/hip_bf16.h>
#include <cstdint>

#define T_SEQ   2048
#define DMODEL  1024
#define NHEADS  16
#define DHEAD   64
#define B_SZ    4
#define M_ROWS  (B_SZ * T_SEQ)   // 8192
// Q pre-scale: (1/sqrt(64)) * log2(e)  -> softmax via exp2 is exact e^S
#define QSCALE  0.1803368801111204f

typedef unsigned short u16;
typedef __attribute__((ext_vector_type(8))) __bf16 bf16x8;
typedef __attribute__((ext_vector_type(4))) float  f32x4;

__device__ __forceinline__ u16 f2bf(float f) {
  uint32_t u = __float_as_uint(f);
  u += 0x7FFF + ((u >> 16) & 1);       // RNE
  return (u16)(u >> 16);
}

__device__ __forceinline__ float fast_exp2(float x) {
  return __builtin_amdgcn_exp2f(x);    // v_exp_f32 (D = 2^S0)
}

__device__ __forceinline__ void gload_lds16(const void* g, void* l) {
  __builtin_amdgcn_global_load_lds(
      (const __attribute__((address_space(1))) void*)g,
      (__attribute__((address_space(3))) void*)l, 16, 0, 0);
}

#define BAR  __builtin_amdgcn_s_barrier()
#define LG0  asm volatile("s_waitcnt lgkmcnt(0)" ::: "memory")
#define VM4  asm volatile("s_waitcnt vmcnt(4)" ::: "memory")
#define VM0  asm volatile("s_waitcnt vmcnt(0)" ::: "memory")
#define PRIO1 __builtin_amdgcn_s_setprio(1)
#define PRIO0 __builtin_amdgcn_s_setprio(0)

// ---------------- fused f32 -> bf16 convert (x + all 4 weights) -------------
__global__ void cvt_all(const float* __restrict__ x,  const float* __restrict__ Wq,
                        const float* __restrict__ Wk, const float* __restrict__ Wv,
                        const float* __restrict__ Wo, u16* __restrict__ xb,
                        u16* __restrict__ Wb) {
  const int NX = (B_SZ * T_SEQ * DMODEL) / 8;   // 1048576 vec8
  const int NW = (DMODEL * DMODEL) / 8;         // 131072 vec8
  int i = blockIdx.x * blockDim.x + threadIdx.x;
  int stride = gridDim.x * blockDim.x;
  for (; i < NX + 4 * NW; i += stride) {
    const float* src; u16* dst; int idx;
    if (i < NX) { src = x; dst = xb; idx = i; }
    else {
      int j = i - NX, w = j >> 17;  // NW = 2^17
      idx = j & (NW - 1);
      src = (w == 0) ? Wq : (w == 1) ? Wk : (w == 2) ? Wv : Wo;
      dst = Wb + (size_t)w * (DMODEL * DMODEL);
    }
    const float4* s4 = (const float4*)src;
    float4 a = s4[2 * idx], b = s4[2 * idx + 1];
    union { u16 u[8]; uint4 v; } o;
    o.u[0] = f2bf(a.x); o.u[1] = f2bf(a.y); o.u[2] = f2bf(a.z); o.u[3] = f2bf(a.w);
    o.u[4] = f2bf(b.x); o.u[5] = f2bf(b.y); o.u[6] = f2bf(b.z); o.u[7] = f2bf(b.w);
    ((uint4*)dst)[idx] = o.v;
  }
}

// ---------------- 256x256 8-phase QKV GEMM (r8 kernel, best measured) -------
__global__ __launch_bounds__(512, 2) void gemm8p_qkv(
    const u16* __restrict__ A, const u16* __restrict__ Wall,
    u16* __restrict__ Qb, u16* __restrict__ Kb, u16* __restrict__ Vtb) {
  constexpr int K = DMODEL;          // 1024, 16 K-tiles
  __shared__ u16 As[2][2][128 * 64];
  __shared__ u16 Bs[2][2][128 * 64];
  const int tid = threadIdx.x;
  const int wid = tid >> 6, lane = tid & 63;
  const int wr = wid >> 2, wc = wid & 3;       // 2M x 4N waves
  const int flat = blockIdx.x;
  const int xcd = flat & 7, serial = flat >> 3;
  const int tm = (serial / 12) * 8 + xcd;      // 0..31 (bijective, 384%8==0)
  const int tn = serial % 12;                  // 0..11
  const int lrow = lane & 15, lq = lane >> 4;
  const int sr = lrow & 7;
  const int srow = tid >> 3;                   // 0..63 staging row
  const int csw = ((tid & 7) ^ (srow & 7)) * 8;
  const int cha = (tid & 7) * 8;               // linear LDS chunk

  const u16* Arow = A    + (size_t)(tm * 256 + srow) * K + csw;
  const u16* Wrow = Wall + (size_t)(tn * 256 + srow) * K + csw;

  auto stageA = [&](int kt, int d, int h) {
    gload_lds16(Arow + (size_t)(h * 128) * K + kt,      &As[d][h][srow * 64 + cha]);
    gload_lds16(Arow + (size_t)(h * 128 + 64) * K + kt, &As[d][h][(64 + srow) * 64 + cha]);
  };
  auto stageB = [&](int kt, int d, int h) {
    gload_lds16(Wrow + (size_t)(h * 128) * K + kt,      &Bs[d][h][srow * 64 + cha]);
    gload_lds16(Wrow + (size_t)(h * 128 + 64) * K + kt, &Bs[d][h][(64 + srow) * 64 + cha]);
  };

  f32x4 acc[8][4];
#pragma unroll
  for (int m = 0; m < 8; m++)
#pragma unroll
    for (int n = 0; n < 4; n++) acc[m][n] = f32x4{0.f, 0.f, 0.f, 0.f};

  auto ldA = [&](bf16x8 (&a)[4][2], int d, int mb) {
#pragma unroll
    for (int m = 0; m < 4; m++)
#pragma unroll
      for (int kk = 0; kk < 2; kk++)
        a[m][kk] = *(const bf16x8*)&As[d][wr][((mb + m) * 16 + lrow) * 64 + (((kk * 4 + lq) ^ sr) * 8)];
  };
  auto ldB = [&](bf16x8 (&b)[2][2], int d, int nb) {
#pragma unroll
    for (int n = 0; n < 2; n++)
#pragma unroll
      for (int kk = 0; kk < 2; kk++)
        b[n][kk] = *(const bf16x8*)&Bs[d][wc >> 1][((wc & 1) * 64 + (nb + n) * 16 + lrow) * 64 + (((kk * 4 + lq) ^ sr) * 8)];
  };
  auto quad = [&](bf16x8 (&a)[4][2], bf16x8 (&b)[2][2], int mb, int nb) {
#pragma unroll
    for (int m = 0; m < 4; m++)
#pragma unroll
      for (int n = 0; n < 2; n++)
#pragma unroll
        for (int kk = 0; kk < 2; kk++)
          acc[mb + m][nb + n] =
              __builtin_amdgcn_mfma_f32_16x16x32_bf16(a[m][kk], b[n][kk], acc[mb + m][nb + n], 0, 0, 0);
  };

  // prologue: T0 fully (B0,B1,A0,A1) + B-halves of T1; wait T0 landed.
  stageB(0, 0, 0); stageB(0, 0, 1);
  stageA(0, 0, 0); stageA(0, 0, 1);
  stageB(64, 1, 0); stageB(64, 1, 1);
  VM4;
  BAR;

#pragma unroll
  for (int i = 0; i < 8; ++i) {
    const int t1 = 2 * i + 1, u0 = 2 * i + 2, u1 = 2 * i + 3;
    bf16x8 aq0[4][2], aq1[4][2], bq0[2][2], bq1[2][2];
    // ---- ph1: t0 quadrant (0,0)
    ldA(aq0, 0, 0); ldB(bq0, 0, 0);
    stageA(t1 * 64, 1, 0);
    BAR; LG0; PRIO1; quad(aq0, bq0, 0, 0); PRIO0; BAR;
    // ---- ph2: t0 quadrant (0,1)
    ldB(bq1, 0, 2);
    stageA(t1 * 64, 1, 1);
    BAR; LG0; PRIO1; quad(aq0, bq1, 0, 2); PRIO0; BAR;
    // ---- ph3: t0 quadrant (1,1)
    ldA(aq1, 0, 4);
    if (u0 < 16) stageB(u0 * 64, 0, 0);
    BAR; LG0; PRIO1; quad(aq1, bq1, 4, 2); PRIO0; BAR;
    // ---- ph4: t0 quadrant (1,0); wait: t1 fully landed
    if (u0 < 16) stageB(u0 * 64, 0, 1);
    BAR; PRIO1; quad(aq1, bq0, 4, 0); PRIO0;
    if (i < 7) { VM4; } else { VM0; }
    BAR;
    // ---- ph5: t1 quadrant (0,0)
    ldA(aq0, 1, 0); ldB(bq0, 1, 0);
    if (u0 < 16) stageA(u0 * 64, 0, 0);
    BAR; LG0; PRIO1; quad(aq0, bq0, 0, 0); PRIO0; BAR;
    // ---- ph6: t1 quadrant (0,1)
    ldB(bq1, 1, 2);
    if (u0 < 16) stageA(u0 * 64, 0, 1);
    BAR; LG0; PRIO1; quad(aq0, bq1, 0, 2); PRIO0; BAR;
    // ---- ph7: t1 quadrant (1,1)
    ldA(aq1, 1, 4);
    if (u1 < 16) stageB(u1 * 64, 1, 0);
    BAR; LG0; PRIO1; quad(aq1, bq1, 4, 2); PRIO0; BAR;
    // ---- ph8: t1 quadrant (1,0); wait: u0 fully landed
    if (u1 < 16) stageB(u1 * 64, 1, 1);
    BAR; PRIO1; quad(aq1, bq0, 4, 0); PRIO0;
    if (i < 7) { VM4; }
    BAR;
  }

  // epilogue: scatter to Q/K/Vt. y and head are wave-uniform.
  const int y = tn >> 2;                       // 0=Q,1=K,2=V
  const int hcol = (tn & 3) * 4 + wc;
  u16* dst = (y == 0) ? Qb : (y == 1) ? Kb : Vtb;
  const float scale = (y == 0) ? QSCALE : 1.0f;
#pragma unroll
  for (int m = 0; m < 8; m++)
#pragma unroll
    for (int n = 0; n < 4; n++)
#pragma unroll
      for (int v = 0; v < 4; v++) {
        int i_ = tm * 256 + wr * 128 + m * 16 + lq * 4 + v;
        int d_ = n * 16 + lrow;
        int b_ = i_ >> 11, t_ = i_ & 2047;
        float val = acc[m][n][v] * scale;
        if (y == 2)
          dst[((size_t)(b_ * NHEADS + hcol) * 64 + d_) * T_SEQ + t_] = f2bf(val);
        else
          dst[((size_t)(b_ * NHEADS + hcol) * T_SEQ + t_) * 64 + d_] = f2bf(val);
      }
}

// ---------------- counted-vmcnt 128x128 NT GEMM (Wo projection) -------------
__global__ __launch_bounds__(256) void gemm3(
    const u16* __restrict__ A, const u16* __restrict__ Wall,
    float* __restrict__ C0) {
  constexpr int K = DMODEL;
  constexpr int NTILES = K / 64;
  constexpr int NT = 8;
  __shared__ u16 As[2][128 * 64];
  __shared__ u16 Bs[2][128 * 64];
  const int tid = threadIdx.x;
  const int wid = tid >> 6, lane = tid & 63;
  const int flat = blockIdx.x;
  const int xcd = flat & 7, serial = flat >> 3;
  const int tm = (serial / NT) * 8 + xcd;
  const int tn = serial % NT;
  const int wr = wid >> 1, wc = wid & 1;
  const int lrow = lane & 15, lq = lane >> 4;
  const int sr = lrow & 7;
  const int srow = lane >> 3;
  const int csw = ((lane & 7) ^ srow) * 8;

  const u16* Arow = A    + (size_t)(tm * 128 + srow) * K + csw;
  const u16* Wrow = Wall + (size_t)(tn * 128 + srow) * K + csw;

  auto stage = [&](int k0, int b) {
#pragma unroll
    for (int it = 0; it < 4; ++it) {
      int rbase = it * 32 + wid * 8;
      gload_lds16(Arow + (size_t)rbase * K + k0, &As[b][rbase * 64]);
      gload_lds16(Wrow + (size_t)rbase * K + k0, &Bs[b][rbase * 64]);
    }
  };

  f32x4 acc[4][4];
#pragma unroll
  for (int m = 0; m < 4; m++)
#pragma unroll
    for (int n = 0; n < 4; n++) acc[m][n] = f32x4{0.f, 0.f, 0.f, 0.f};

  auto compute = [&](int b) {
#pragma unroll
    for (int kk = 0; kk < 2; ++kk) {
      bf16x8 a[4], bb[4];
      const int co = ((kk * 4 + lq) ^ sr) * 8;
#pragma unroll
      for (int m = 0; m < 4; m++)
        a[m] = *(const bf16x8*)&As[b][(wr * 64 + m * 16 + lrow) * 64 + co];
#pragma unroll
      for (int n = 0; n < 4; n++)
        bb[n] = *(const bf16x8*)&Bs[b][(wc * 64 + n * 16 + lrow) * 64 + co];
#pragma unroll
      for (int m = 0; m < 4; m++)
#pragma unroll
        for (int n = 0; n < 4; n++)
          acc[m][n] = __builtin_amdgcn_mfma_f32_16x16x32_bf16(a[m], bb[n], acc[m][n], 0, 0, 0);
    }
  };

  stage(0, 0);
  stage(64, 1);
  asm volatile("s_waitcnt vmcnt(8)" ::: "memory");
  __builtin_amdgcn_s_barrier();

  for (int t = 0; t < NTILES; t += 2) {
    compute(0);
    asm volatile("" ::: "memory");
    __builtin_amdgcn_s_barrier();
    if (t + 2 < NTILES) {
      stage((t + 2) * 64, 0);
      asm volatile("s_waitcnt vmcnt(8)" ::: "memory");
    } else {
      asm volatile("s_waitcnt vmcnt(0)" ::: "memory");
    }
    __builtin_amdgcn_s_barrier();
    compute(1);
    if (t + 3 < NTILES) {
      asm volatile("" ::: "memory");
      __builtin_amdgcn_s_barrier();
      stage((t + 3) * 64, 1);
      asm volatile("s_waitcnt vmcnt(8)" ::: "memory");
      __builtin_amdgcn_s_barrier();
    }
  }

#pragma unroll
  for (int m = 0; m < 4; m++)
#pragma unroll
    for (int n = 0; n < 4; n++)
#pragma unroll
      for (int v = 0; v < 4; v++) {
        int i = tm * 128 + wr * 64 + m * 16 + lq * 4 + v;
        int j = tn * 128 + wc * 64 + n * 16 + lrow;
        C0[(size_t)i * DMODEL + j] = acc[m][n][v];
      }
}

// ---------------- causal flash attention v4: 4 q-tiles per block ------------
// Q,K: [BH,T,64] bf16 (Q pre-scaled). Vt: [BH,64,T] bf16.
// Block = (i, bh), i in 0..7: owns q-tiles {i, 31-i, 15-i, 16+i} (covers 0..31
// over i=0..7; constant 66 applies/block -> balanced). Each staged K/V tile
// feeds up to 4 applies -> stage+barrier events drop 42% vs 2-tile version.
// Grid 512 (8 i x 64 bh), XCD swizzle keeps 8 bh per XCD (K/V 4MB, L2-fit).
__global__ __launch_bounds__(256) void flash_attn(
    const u16* __restrict__ Q, const u16* __restrict__ Kg,
    const u16* __restrict__ Vt, u16* __restrict__ Ao) {
  __shared__ u16 Ks[2][64 * 64];
  __shared__ u16 Vs[2][64 * 64];
  __shared__ u16 Ps[4][16 * 64];
  const int tid = threadIdx.x, wid = tid >> 6, lane = tid & 63;
  const int flat = blockIdx.x;
  const int xcd = flat & 7, serial = flat >> 3;   // serial 0..63
  const int iq = serial & 7;
  const int bh = (serial >> 3) * 8 + xcd;         // 0..63
  int qt[4] = { iq, 31 - iq, 15 - iq, 16 + iq };
  const int kmax = 31 - iq;                       // max over qt[]
  const int lrow = lane & 15, lq = lane >> 4;
  const int sr = lrow & 7;
  const int srow = lane >> 3;
  const int csw = ((lane & 7) ^ srow) * 8;        // pre-swizzled source chunk

  const u16* qbase = Q + ((size_t)bh * T_SEQ + wid * 16 + lrow) * 64 + lq * 8;
  bf16x8 qf0[4], qf1[4];
#pragma unroll
  for (int j = 0; j < 4; j++) {
    qf0[j] = *(const bf16x8*)(qbase + (size_t)qt[j] * 4096);
    qf1[j] = *(const bf16x8*)(qbase + (size_t)qt[j] * 4096 + 32);
  }

  bf16x8 ones;
  {
    union { u16 u; __bf16 b; } c; c.u = 0x3F80;
#pragma unroll
    for (int j = 0; j < 8; j++) ones[j] = c.b;
  }

  f32x4 po[4][4], l4[4];
#pragma unroll
  for (int j = 0; j < 4; j++) {
#pragma unroll
    for (int n = 0; n < 4; n++) po[j][n] = f32x4{0.f, 0.f, 0.f, 0.f};
    l4[j] = f32x4{0.f, 0.f, 0.f, 0.f};
  }

  auto stage = [&](int kt, int b) {
#pragma unroll
    for (int it = 0; it < 2; ++it) {
      int rbase = it * 32 + wid * 8;
      gload_lds16(Kg + ((size_t)bh * T_SEQ + kt * 64 + rbase + srow) * 64 + csw,
                  &Ks[b][rbase * 64]);
      gload_lds16(Vt + ((size_t)bh * 64 + rbase + srow) * T_SEQ + kt * 64 + csw,
                  &Vs[b][rbase * 64]);
    }
  };

  stage(0, 0);
  __syncthreads();
  int cur = 0;

  for (int kt = 0; kt <= kmax; ++kt) {
    if (kt < kmax) stage(kt + 1, cur ^ 1);  // prefetch next tile

    bf16x8 kf0[4], kf1[4];
#pragma unroll
    for (int n = 0; n < 4; n++) {
      kf0[n] = *(const bf16x8*)&Ks[cur][(n * 16 + lrow) * 64 + ((lq ^ sr) * 8)];
      kf1[n] = *(const bf16x8*)&Ks[cur][(n * 16 + lrow) * 64 + (((lq + 4) ^ sr) * 8)];
    }

    auto apply = [&](const bf16x8& q0, const bf16x8& q1,
                     f32x4 (&poj)[4], f32x4& lj, bool diag) {
      f32x4 s[4];
#pragma unroll
      for (int n = 0; n < 4; n++) {
        f32x4 a = f32x4{0.f, 0.f, 0.f, 0.f};
        a = __builtin_amdgcn_mfma_f32_16x16x32_bf16(q0, kf0[n], a, 0, 0, 0);
        a = __builtin_amdgcn_mfma_f32_16x16x32_bf16(q1, kf1[n], a, 0, 0, 0);
        s[n] = a;
      }
      if (diag) {
#pragma unroll
        for (int n = 0; n < 4; n++)
#pragma unroll
          for (int v = 0; v < 4; v++) {
            int kcol = n * 16 + lrow;
            int qrow = wid * 16 + lq * 4 + v;
            if (kcol > qrow) s[n][v] = -1e30f;
          }
      }
      // P = exp2(S'); store truncated bf16 (ratio-cancelling bias)
#pragma unroll
      for (int n = 0; n < 4; n++)
#pragma unroll
        for (int v = 0; v < 4; v++) {
          float p = fast_exp2(s[n][v]);
          int col = n * 16 + lrow;
          int r = lq * 4 + v;
          Ps[wid][r * 64 + (((col >> 3) ^ (r & 7)) * 8) + (col & 7)] =
              (u16)(__float_as_uint(p) >> 16);
        }
#pragma unroll
      for (int kk = 0; kk < 2; kk++) {
        bf16x8 pa = *(const bf16x8*)&Ps[wid][lrow * 64 + (((kk * 4 + lq) ^ sr) * 8)];
#pragma unroll
        for (int n = 0; n < 4; n++) {
          bf16x8 vf = *(const bf16x8*)&Vs[cur][(n * 16 + lrow) * 64 + (((kk * 4 + lq) ^ sr) * 8)];
          poj[n] = __builtin_amdgcn_mfma_f32_16x16x32_bf16(pa, vf, poj[n], 0, 0, 0);
        }
        lj = __builtin_amdgcn_mfma_f32_16x16x32_bf16(pa, ones, lj, 0, 0, 0);
      }
    };

#pragma unroll
    for (int j = 0; j < 4; j++)
      if (kt <= qt[j]) apply(qf0[j], qf1[j], po[j], l4[j], kt == qt[j]);

    asm volatile("s_waitcnt vmcnt(0)" ::: "memory");
    __syncthreads();
    cur ^= 1;
  }

  const int b_ = bh >> 4, h_ = bh & 15;
#pragma unroll
  for (int j = 0; j < 4; j++) {
    float rl[4];
#pragma unroll
    for (int v = 0; v < 4; v++) rl[v] = 1.0f / l4[j][v];
#pragma unroll
    for (int n = 0; n < 4; n++)
#pragma unroll
      for (int v = 0; v < 4; v++) {
        int t_ = qt[j] * 64 + wid * 16 + lq * 4 + v;
        int col = h_ * 64 + n * 16 + lrow;
        Ao[((size_t)b_ * T_SEQ + t_) * DMODEL + col] = f2bf(po[j][n][v] * rl[v]);
      }
  }
}

// ---------------- launch -----------------------------------------------------
extern "C" void kernel_launch(void* const* d_in, const int* in_sizes, int n_in,
                              void* d_out, int out_size, void* d_ws, size_t ws_size,
                              hipStream_t stream) {
  const float* x  = (const float*)d_in[0];
  const float* Wq = (const float*)d_in[1];
  const float* Wk = (const float*)d_in[2];
  const float* Wv = (const float*)d_in[3];
  const float* Wo = (const float*)d_in[4];
  float* out = (float*)d_out;

  char* ws = (char*)d_ws;
  u16* xb  = (u16*)(ws);                       // 16.78 MB, reused as attn-out
  u16* Wb  = (u16*)(ws + 16777216);            // 4 x 2 MB bf16 weights (QKV contiguous)
  u16* Qb  = (u16*)(ws + 25165824);            // [BH,T,64]
  u16* Kb  = (u16*)(ws + 41943040);            // [BH,T,64]
  u16* Vtb = (u16*)(ws + 58720256);            // [BH,64,T]
  u16* Aob = xb;                               // attn output, bf16 [B*T, 1024]

  cvt_all<<<2048, 256, 0, stream>>>(x, Wq, Wk, Wv, Wo, xb, Wb);

  // fused QKV: M=8192 x N=3072, 256^2 8-phase (r8 kernel, best measured)
  gemm8p_qkv<<<384, 512, 0, stream>>>(xb, Wb, Qb, Kb, Vtb);

  flash_attn<<<512, 256, 0, stream>>>(Qb, Kb, Vtb, Aob);

  gemm3<<<512, 256, 0, stream>>>(Aob, Wb + 3 * 1048576, out);
}

// Round 11
// 185.234 us; speedup vs baseline: 1.0734x; 1.0040x over previous
//
#include <hip/hip_runtime.h>
#include <hip/hip_bf16.h>
#include <cstdint>

#define T_SEQ   2048
#define DMODEL  1024
#define NHEADS  16
#define DHEAD   64
#define B_SZ    4
#define M_ROWS  (B_SZ * T_SEQ)   // 8192
// Q pre-scale: (1/sqrt(64)) * log2(e)  -> softmax via exp2 is exact e^S
#define QSCALE  0.1803368801111204f

typedef unsigned short u16;
typedef __attribute__((ext_vector_type(8))) __bf16 bf16x8;
typedef __attribute__((ext_vector_type(4))) float  f32x4;

__device__ __forceinline__ u16 f2bf(float f) {
  uint32_t u = __float_as_uint(f);
  u += 0x7FFF + ((u >> 16) & 1);       // RNE
  return (u16)(u >> 16);
}

__device__ __forceinline__ float fast_exp2(float x) {
  return __builtin_amdgcn_exp2f(x);    // v_exp_f32 (D = 2^S0)
}

__device__ __forceinline__ void gload_lds16(const void* g, void* l) {
  __builtin_amdgcn_global_load_lds(
      (const __attribute__((address_space(1))) void*)g,
      (__attribute__((address_space(3))) void*)l, 16, 0, 0);
}

#define BAR  __builtin_amdgcn_s_barrier()
#define LG0  asm volatile("s_waitcnt lgkmcnt(0)" ::: "memory")
#define VM4  asm volatile("s_waitcnt vmcnt(4)" ::: "memory")
#define VM0  asm volatile("s_waitcnt vmcnt(0)" ::: "memory")
#define PRIO1 __builtin_amdgcn_s_setprio(1)
#define PRIO0 __builtin_amdgcn_s_setprio(0)

// ---------------- fused f32 -> bf16 convert (x + all 4 weights) -------------
__global__ void cvt_all(const float* __restrict__ x,  const float* __restrict__ Wq,
                        const float* __restrict__ Wk, const float* __restrict__ Wv,
                        const float* __restrict__ Wo, u16* __restrict__ xb,
                        u16* __restrict__ Wb) {
  const int NX = (B_SZ * T_SEQ * DMODEL) / 8;   // 1048576 vec8
  const int NW = (DMODEL * DMODEL) / 8;         // 131072 vec8
  int i = blockIdx.x * blockDim.x + threadIdx.x;
  int stride = gridDim.x * blockDim.x;
  for (; i < NX + 4 * NW; i += stride) {
    const float* src; u16* dst; int idx;
    if (i < NX) { src = x; dst = xb; idx = i; }
    else {
      int j = i - NX, w = j >> 17;  // NW = 2^17
      idx = j & (NW - 1);
      src = (w == 0) ? Wq : (w == 1) ? Wk : (w == 2) ? Wv : Wo;
      dst = Wb + (size_t)w * (DMODEL * DMODEL);
    }
    const float4* s4 = (const float4*)src;
    float4 a = s4[2 * idx], b = s4[2 * idx + 1];
    union { u16 u[8]; uint4 v; } o;
    o.u[0] = f2bf(a.x); o.u[1] = f2bf(a.y); o.u[2] = f2bf(a.z); o.u[3] = f2bf(a.w);
    o.u[4] = f2bf(b.x); o.u[5] = f2bf(b.y); o.u[6] = f2bf(b.z); o.u[7] = f2bf(b.w);
    ((uint4*)dst)[idx] = o.v;
  }
}

// ---------------- 256x256 8-phase QKV GEMM (r8 kernel, best measured) -------
__global__ __launch_bounds__(512, 2) void gemm8p_qkv(
    const u16* __restrict__ A, const u16* __restrict__ Wall,
    u16* __restrict__ Qb, u16* __restrict__ Kb, u16* __restrict__ Vtb) {
  constexpr int K = DMODEL;          // 1024, 16 K-tiles
  __shared__ u16 As[2][2][128 * 64];
  __shared__ u16 Bs[2][2][128 * 64];
  const int tid = threadIdx.x;
  const int wid = tid >> 6, lane = tid & 63;
  const int wr = wid >> 2, wc = wid & 3;       // 2M x 4N waves
  const int flat = blockIdx.x;
  const int xcd = flat & 7, serial = flat >> 3;
  const int tm = (serial / 12) * 8 + xcd;      // 0..31 (bijective, 384%8==0)
  const int tn = serial % 12;                  // 0..11
  const int lrow = lane & 15, lq = lane >> 4;
  const int sr = lrow & 7;
  const int srow = tid >> 3;                   // 0..63 staging row
  const int csw = ((tid & 7) ^ (srow & 7)) * 8;
  const int cha = (tid & 7) * 8;               // linear LDS chunk

  const u16* Arow = A    + (size_t)(tm * 256 + srow) * K + csw;
  const u16* Wrow = Wall + (size_t)(tn * 256 + srow) * K + csw;

  auto stageA = [&](int kt, int d, int h) {
    gload_lds16(Arow + (size_t)(h * 128) * K + kt,      &As[d][h][srow * 64 + cha]);
    gload_lds16(Arow + (size_t)(h * 128 + 64) * K + kt, &As[d][h][(64 + srow) * 64 + cha]);
  };
  auto stageB = [&](int kt, int d, int h) {
    gload_lds16(Wrow + (size_t)(h * 128) * K + kt,      &Bs[d][h][srow * 64 + cha]);
    gload_lds16(Wrow + (size_t)(h * 128 + 64) * K + kt, &Bs[d][h][(64 + srow) * 64 + cha]);
  };

  f32x4 acc[8][4];
#pragma unroll
  for (int m = 0; m < 8; m++)
#pragma unroll
    for (int n = 0; n < 4; n++) acc[m][n] = f32x4{0.f, 0.f, 0.f, 0.f};

  auto ldA = [&](bf16x8 (&a)[4][2], int d, int mb) {
#pragma unroll
    for (int m = 0; m < 4; m++)
#pragma unroll
      for (int kk = 0; kk < 2; kk++)
        a[m][kk] = *(const bf16x8*)&As[d][wr][((mb + m) * 16 + lrow) * 64 + (((kk * 4 + lq) ^ sr) * 8)];
  };
  auto ldB = [&](bf16x8 (&b)[2][2], int d, int nb) {
#pragma unroll
    for (int n = 0; n < 2; n++)
#pragma unroll
      for (int kk = 0; kk < 2; kk++)
        b[n][kk] = *(const bf16x8*)&Bs[d][wc >> 1][((wc & 1) * 64 + (nb + n) * 16 + lrow) * 64 + (((kk * 4 + lq) ^ sr) * 8)];
  };
  auto quad = [&](bf16x8 (&a)[4][2], bf16x8 (&b)[2][2], int mb, int nb) {
#pragma unroll
    for (int m = 0; m < 4; m++)
#pragma unroll
      for (int n = 0; n < 2; n++)
#pragma unroll
        for (int kk = 0; kk < 2; kk++)
          acc[mb + m][nb + n] =
              __builtin_amdgcn_mfma_f32_16x16x32_bf16(a[m][kk], b[n][kk], acc[mb + m][nb + n], 0, 0, 0);
  };

  // prologue: T0 fully (B0,B1,A0,A1) + B-halves of T1; wait T0 landed.
  stageB(0, 0, 0); stageB(0, 0, 1);
  stageA(0, 0, 0); stageA(0, 0, 1);
  stageB(64, 1, 0); stageB(64, 1, 1);
  VM4;
  BAR;

#pragma unroll
  for (int i = 0; i < 8; ++i) {
    const int t1 = 2 * i + 1, u0 = 2 * i + 2, u1 = 2 * i + 3;
    bf16x8 aq0[4][2], aq1[4][2], bq0[2][2], bq1[2][2];
    // ---- ph1: t0 quadrant (0,0)
    ldA(aq0, 0, 0); ldB(bq0, 0, 0);
    stageA(t1 * 64, 1, 0);
    BAR; LG0; PRIO1; quad(aq0, bq0, 0, 0); PRIO0; BAR;
    // ---- ph2: t0 quadrant (0,1)
    ldB(bq1, 0, 2);
    stageA(t1 * 64, 1, 1);
    BAR; LG0; PRIO1; quad(aq0, bq1, 0, 2); PRIO0; BAR;
    // ---- ph3: t0 quadrant (1,1)
    ldA(aq1, 0, 4);
    if (u0 < 16) stageB(u0 * 64, 0, 0);
    BAR; LG0; PRIO1; quad(aq1, bq1, 4, 2); PRIO0; BAR;
    // ---- ph4: t0 quadrant (1,0); wait: t1 fully landed
    if (u0 < 16) stageB(u0 * 64, 0, 1);
    BAR; PRIO1; quad(aq1, bq0, 4, 0); PRIO0;
    if (i < 7) { VM4; } else { VM0; }
    BAR;
    // ---- ph5: t1 quadrant (0,0)
    ldA(aq0, 1, 0); ldB(bq0, 1, 0);
    if (u0 < 16) stageA(u0 * 64, 0, 0);
    BAR; LG0; PRIO1; quad(aq0, bq0, 0, 0); PRIO0; BAR;
    // ---- ph6: t1 quadrant (0,1)
    ldB(bq1, 1, 2);
    if (u0 < 16) stageA(u0 * 64, 0, 1);
    BAR; LG0; PRIO1; quad(aq0, bq1, 0, 2); PRIO0; BAR;
    // ---- ph7: t1 quadrant (1,1)
    ldA(aq1, 1, 4);
    if (u1 < 16) stageB(u1 * 64, 1, 0);
    BAR; LG0; PRIO1; quad(aq1, bq1, 4, 2); PRIO0; BAR;
    // ---- ph8: t1 quadrant (1,0); wait: u0 fully landed
    if (u1 < 16) stageB(u1 * 64, 1, 1);
    BAR; PRIO1; quad(aq1, bq0, 4, 0); PRIO0;
    if (i < 7) { VM4; }
    BAR;
  }

  // epilogue: scatter to Q/K/Vt. y and head are wave-uniform.
  const int y = tn >> 2;                       // 0=Q,1=K,2=V
  const int hcol = (tn & 3) * 4 + wc;
  u16* dst = (y == 0) ? Qb : (y == 1) ? Kb : Vtb;
  const float scale = (y == 0) ? QSCALE : 1.0f;
#pragma unroll
  for (int m = 0; m < 8; m++)
#pragma unroll
    for (int n = 0; n < 4; n++)
#pragma unroll
      for (int v = 0; v < 4; v++) {
        int i_ = tm * 256 + wr * 128 + m * 16 + lq * 4 + v;
        int d_ = n * 16 + lrow;
        int b_ = i_ >> 11, t_ = i_ & 2047;
        float val = acc[m][n][v] * scale;
        if (y == 2)
          dst[((size_t)(b_ * NHEADS + hcol) * 64 + d_) * T_SEQ + t_] = f2bf(val);
        else
          dst[((size_t)(b_ * NHEADS + hcol) * T_SEQ + t_) * 64 + d_] = f2bf(val);
      }
}

// ---------------- counted-vmcnt 128x128 NT GEMM (Wo projection) -------------
__global__ __launch_bounds__(256) void gemm3(
    const u16* __restrict__ A, const u16* __restrict__ Wall,
    float* __restrict__ C0) {
  constexpr int K = DMODEL;
  constexpr int NTILES = K / 64;
  constexpr int NT = 8;
  __shared__ u16 As[2][128 * 64];
  __shared__ u16 Bs[2][128 * 64];
  const int tid = threadIdx.x;
  const int wid = tid >> 6, lane = tid & 63;
  const int flat = blockIdx.x;
  const int xcd = flat & 7, serial = flat >> 3;
  const int tm = (serial / NT) * 8 + xcd;
  const int tn = serial % NT;
  const int wr = wid >> 1, wc = wid & 1;
  const int lrow = lane & 15, lq = lane >> 4;
  const int sr = lrow & 7;
  const int srow = lane >> 3;
  const int csw = ((lane & 7) ^ srow) * 8;

  const u16* Arow = A    + (size_t)(tm * 128 + srow) * K + csw;
  const u16* Wrow = Wall + (size_t)(tn * 128 + srow) * K + csw;

  auto stage = [&](int k0, int b) {
#pragma unroll
    for (int it = 0; it < 4; ++it) {
      int rbase = it * 32 + wid * 8;
      gload_lds16(Arow + (size_t)rbase * K + k0, &As[b][rbase * 64]);
      gload_lds16(Wrow + (size_t)rbase * K + k0, &Bs[b][rbase * 64]);
    }
  };

  f32x4 acc[4][4];
#pragma unroll
  for (int m = 0; m < 4; m++)
#pragma unroll
    for (int n = 0; n < 4; n++) acc[m][n] = f32x4{0.f, 0.f, 0.f, 0.f};

  auto compute = [&](int b) {
#pragma unroll
    for (int kk = 0; kk < 2; ++kk) {
      bf16x8 a[4], bb[4];
      const int co = ((kk * 4 + lq) ^ sr) * 8;
#pragma unroll
      for (int m = 0; m < 4; m++)
        a[m] = *(const bf16x8*)&As[b][(wr * 64 + m * 16 + lrow) * 64 + co];
#pragma unroll
      for (int n = 0; n < 4; n++)
        bb[n] = *(const bf16x8*)&Bs[b][(wc * 64 + n * 16 + lrow) * 64 + co];
#pragma unroll
      for (int m = 0; m < 4; m++)
#pragma unroll
        for (int n = 0; n < 4; n++)
          acc[m][n] = __builtin_amdgcn_mfma_f32_16x16x32_bf16(a[m], bb[n], acc[m][n], 0, 0, 0);
    }
  };

  stage(0, 0);
  stage(64, 1);
  asm volatile("s_waitcnt vmcnt(8)" ::: "memory");
  __builtin_amdgcn_s_barrier();

  for (int t = 0; t < NTILES; t += 2) {
    compute(0);
    asm volatile("" ::: "memory");
    __builtin_amdgcn_s_barrier();
    if (t + 2 < NTILES) {
      stage((t + 2) * 64, 0);
      asm volatile("s_waitcnt vmcnt(8)" ::: "memory");
    } else {
      asm volatile("s_waitcnt vmcnt(0)" ::: "memory");
    }
    __builtin_amdgcn_s_barrier();
    compute(1);
    if (t + 3 < NTILES) {
      asm volatile("" ::: "memory");
      __builtin_amdgcn_s_barrier();
      stage((t + 3) * 64, 1);
      asm volatile("s_waitcnt vmcnt(8)" ::: "memory");
      __builtin_amdgcn_s_barrier();
    }
  }

#pragma unroll
  for (int m = 0; m < 4; m++)
#pragma unroll
    for (int n = 0; n < 4; n++)
#pragma unroll
      for (int v = 0; v < 4; v++) {
        int i = tm * 128 + wr * 64 + m * 16 + lq * 4 + v;
        int j = tn * 128 + wc * 64 + n * 16 + lrow;
        C0[(size_t)i * DMODEL + j] = acc[m][n][v];
      }
}

// ---------------- causal flash attention v4 + T5 setprio --------------------
// Q,K: [BH,T,64] bf16 (Q pre-scaled). Vt: [BH,64,T] bf16.
// Block = (i, bh), i in 0..7: owns q-tiles {i, 31-i, 15-i, 16+i}.
// setprio(1) wraps the QK^T and PV MFMA clusters (T5, m191 +4-7% attn);
// exp/softmax stays prio 0 so MFMA-entering waves win CU arbitration.
__global__ __launch_bounds__(256) void flash_attn(
    const u16* __restrict__ Q, const u16* __restrict__ Kg,
    const u16* __restrict__ Vt, u16* __restrict__ Ao) {
  __shared__ u16 Ks[2][64 * 64];
  __shared__ u16 Vs[2][64 * 64];
  __shared__ u16 Ps[4][16 * 64];
  const int tid = threadIdx.x, wid = tid >> 6, lane = tid & 63;
  const int flat = blockIdx.x;
  const int xcd = flat & 7, serial = flat >> 3;   // serial 0..63
  const int iq = serial & 7;
  const int bh = (serial >> 3) * 8 + xcd;         // 0..63
  int qt[4] = { iq, 31 - iq, 15 - iq, 16 + iq };
  const int kmax = 31 - iq;                       // max over qt[]
  const int lrow = lane & 15, lq = lane >> 4;
  const int sr = lrow & 7;
  const int srow = lane >> 3;
  const int csw = ((lane & 7) ^ srow) * 8;        // pre-swizzled source chunk

  const u16* qbase = Q + ((size_t)bh * T_SEQ + wid * 16 + lrow) * 64 + lq * 8;
  bf16x8 qf0[4], qf1[4];
#pragma unroll
  for (int j = 0; j < 4; j++) {
    qf0[j] = *(const bf16x8*)(qbase + (size_t)qt[j] * 4096);
    qf1[j] = *(const bf16x8*)(qbase + (size_t)qt[j] * 4096 + 32);
  }

  bf16x8 ones;
  {
    union { u16 u; __bf16 b; } c; c.u = 0x3F80;
#pragma unroll
    for (int j = 0; j < 8; j++) ones[j] = c.b;
  }

  f32x4 po[4][4], l4[4];
#pragma unroll
  for (int j = 0; j < 4; j++) {
#pragma unroll
    for (int n = 0; n < 4; n++) po[j][n] = f32x4{0.f, 0.f, 0.f, 0.f};
    l4[j] = f32x4{0.f, 0.f, 0.f, 0.f};
  }

  auto stage = [&](int kt, int b) {
#pragma unroll
    for (int it = 0; it < 2; ++it) {
      int rbase = it * 32 + wid * 8;
      gload_lds16(Kg + ((size_t)bh * T_SEQ + kt * 64 + rbase + srow) * 64 + csw,
                  &Ks[b][rbase * 64]);
      gload_lds16(Vt + ((size_t)bh * 64 + rbase + srow) * T_SEQ + kt * 64 + csw,
                  &Vs[b][rbase * 64]);
    }
  };

  stage(0, 0);
  __syncthreads();
  int cur = 0;

  for (int kt = 0; kt <= kmax; ++kt) {
    if (kt < kmax) stage(kt + 1, cur ^ 1);  // prefetch next tile

    bf16x8 kf0[4], kf1[4];
#pragma unroll
    for (int n = 0; n < 4; n++) {
      kf0[n] = *(const bf16x8*)&Ks[cur][(n * 16 + lrow) * 64 + ((lq ^ sr) * 8)];
      kf1[n] = *(const bf16x8*)&Ks[cur][(n * 16 + lrow) * 64 + (((lq + 4) ^ sr) * 8)];
    }

    auto apply = [&](const bf16x8& q0, const bf16x8& q1,
                     f32x4 (&poj)[4], f32x4& lj, bool diag) {
      f32x4 s[4];
      PRIO1;
#pragma unroll
      for (int n = 0; n < 4; n++) {
        f32x4 a = f32x4{0.f, 0.f, 0.f, 0.f};
        a = __builtin_amdgcn_mfma_f32_16x16x32_bf16(q0, kf0[n], a, 0, 0, 0);
        a = __builtin_amdgcn_mfma_f32_16x16x32_bf16(q1, kf1[n], a, 0, 0, 0);
        s[n] = a;
      }
      PRIO0;
      if (diag) {
#pragma unroll
        for (int n = 0; n < 4; n++)
#pragma unroll
          for (int v = 0; v < 4; v++) {
            int kcol = n * 16 + lrow;
            int qrow = wid * 16 + lq * 4 + v;
            if (kcol > qrow) s[n][v] = -1e30f;
          }
      }
      // P = exp2(S'); store truncated bf16 (ratio-cancelling bias)
#pragma unroll
      for (int n = 0; n < 4; n++)
#pragma unroll
        for (int v = 0; v < 4; v++) {
          float p = fast_exp2(s[n][v]);
          int col = n * 16 + lrow;
          int r = lq * 4 + v;
          Ps[wid][r * 64 + (((col >> 3) ^ (r & 7)) * 8) + (col & 7)] =
              (u16)(__float_as_uint(p) >> 16);
        }
      PRIO1;
#pragma unroll
      for (int kk = 0; kk < 2; kk++) {
        bf16x8 pa = *(const bf16x8*)&Ps[wid][lrow * 64 + (((kk * 4 + lq) ^ sr) * 8)];
#pragma unroll
        for (int n = 0; n < 4; n++) {
          bf16x8 vf = *(const bf16x8*)&Vs[cur][(n * 16 + lrow) * 64 + (((kk * 4 + lq) ^ sr) * 8)];
          poj[n] = __builtin_amdgcn_mfma_f32_16x16x32_bf16(pa, vf, poj[n], 0, 0, 0);
        }
        lj = __builtin_amdgcn_mfma_f32_16x16x32_bf16(pa, ones, lj, 0, 0, 0);
      }
      PRIO0;
    };

#pragma unroll
    for (int j = 0; j < 4; j++)
      if (kt <= qt[j]) apply(qf0[j], qf1[j], po[j], l4[j], kt == qt[j]);

    asm volatile("s_waitcnt vmcnt(0)" ::: "memory");
    __syncthreads();
    cur ^= 1;
  }

  const int b_ = bh >> 4, h_ = bh & 15;
#pragma unroll
  for (int j = 0; j < 4; j++) {
    float rl[4];
#pragma unroll
    for (int v = 0; v < 4; v++) rl[v] = 1.0f / l4[j][v];
#pragma unroll
    for (int n = 0; n < 4; n++)
#pragma unroll
      for (int v = 0; v < 4; v++) {
        int t_ = qt[j] * 64 + wid * 16 + lq * 4 + v;
        int col = h_ * 64 + n * 16 + lrow;
        Ao[((size_t)b_ * T_SEQ + t_) * DMODEL + col] = f2bf(po[j][n][v] * rl[v]);
      }
  }
}

// ---------------- launch -----------------------------------------------------
extern "C" void kernel_launch(void* const* d_in, const int* in_sizes, int n_in,
                              void* d_out, int out_size, void* d_ws, size_t ws_size,
                              hipStream_t stream) {
  const float* x  = (const float*)d_in[0];
  const float* Wq = (const float*)d_in[1];
  const float* Wk = (const float*)d_in[2];
  const float* Wv = (const float*)d_in[3];
  const float* Wo = (const float*)d_in[4];
  float* out = (float*)d_out;

  char* ws = (char*)d_ws;
  u16* xb  = (u16*)(ws);                       // 16.78 MB, reused as attn-out
  u16* Wb  = (u16*)(ws + 16777216);            // 4 x 2 MB bf16 weights (QKV contiguous)
  u16* Qb  = (u16*)(ws + 25165824);            // [BH,T,64]
  u16* Kb  = (u16*)(ws + 41943040);            // [BH,T,64]
  u16* Vtb = (u16*)(ws + 58720256);            // [BH,64,T]
  u16* Aob = xb;                               // attn output, bf16 [B*T, 1024]

  cvt_all<<<2048, 256, 0, stream>>>(x, Wq, Wk, Wv, Wo, xb, Wb);

  // fused QKV: M=8192 x N=3072, 256^2 8-phase (r8 kernel, best measured)
  gemm8p_qkv<<<384, 512, 0, stream>>>(xb, Wb, Qb, Kb, Vtb);

  flash_attn<<<512, 256, 0, stream>>>(Qb, Kb, Vtb, Aob);

  gemm3<<<512, 256, 0, stream>>>(Aob, Wb + 3 * 1048576, out);
}